// Round 1
// baseline (256.787 us; speedup 1.0000x reference)
//
#include <hip/hip_runtime.h>
#include <hip/hip_bf16.h>

#define NROWS 16384
#define KDIM  512
#define EDIM  256

// ---------------------------------------------------------------------------
// Kernel 1: row-sum of adj (1 GiB streaming read). One block per row.
// Each thread sums 16 float4 (64 floats); wave shuffle reduce; LDS across waves.
// ---------------------------------------------------------------------------
__global__ __launch_bounds__(256) void rowsum_kernel(const float* __restrict__ adj,
                                                     float* __restrict__ rs) {
    const int row = blockIdx.x;
    const int tid = threadIdx.x;
    const float4* p = (const float4*)(adj + (size_t)row * NROWS);

    float s = 0.f;
#pragma unroll
    for (int i = 0; i < 16; ++i) {
        float4 v = p[tid + i * 256];
        s += (v.x + v.y) + (v.z + v.w);
    }
    // wave (64-lane) reduction
#pragma unroll
    for (int off = 32; off > 0; off >>= 1)
        s += __shfl_down(s, off, 64);

    __shared__ float red[4];
    if ((tid & 63) == 0) red[tid >> 6] = s;
    __syncthreads();
    if (tid == 0) rs[row] = (red[0] + red[1]) + (red[2] + red[3]);
}

// ---------------------------------------------------------------------------
// Kernel 2: out[i][j] = relu(d[i] * sum_k x[i][k] * W[j][k])
//   d[i] = 1/(rs[i]+1) + 1
// Tiled fp32 SGEMM: 64x64 block tile, BK=16, 256 threads, 4x4 micro-tile.
// ---------------------------------------------------------------------------
#define GM 64
#define GN 64
#define GK 16

__global__ __launch_bounds__(256) void gemm_relu_kernel(const float* __restrict__ x,
                                                        const float* __restrict__ W,
                                                        const float* __restrict__ rs,
                                                        float* __restrict__ out) {
    __shared__ float As[GK][GM];   // As[k][m] = x[row0+m][k0+k]
    __shared__ float Bs[GK][GN];   // Bs[k][n] = W[col0+n][k0+k]

    const int row0 = blockIdx.x * GM;
    const int col0 = blockIdx.y * GN;
    const int tid  = threadIdx.x;
    const int tx   = tid & 15;    // 0..15 -> output cols (x4)
    const int ty   = tid >> 4;    // 0..15 -> output rows (x4)

    // staging indices: 256 threads load 64 rows x 16 k (float4 per thread)
    const int lm = tid >> 2;          // 0..63
    const int lk = (tid & 3) * 4;     // 0,4,8,12

    float acc[4][4] = {};

    for (int k0 = 0; k0 < KDIM; k0 += GK) {
        float4 av = *(const float4*)(x + (size_t)(row0 + lm) * KDIM + k0 + lk);
        float4 bv = *(const float4*)(W + (size_t)(col0 + lm) * KDIM + k0 + lk);
        As[lk + 0][lm] = av.x; As[lk + 1][lm] = av.y;
        As[lk + 2][lm] = av.z; As[lk + 3][lm] = av.w;
        Bs[lk + 0][lm] = bv.x; Bs[lk + 1][lm] = bv.y;
        Bs[lk + 2][lm] = bv.z; Bs[lk + 3][lm] = bv.w;
        __syncthreads();

#pragma unroll
        for (int k = 0; k < GK; ++k) {
            float a[4], b[4];
            *(float4*)a = *(const float4*)&As[k][ty * 4];
            *(float4*)b = *(const float4*)&Bs[k][tx * 4];
#pragma unroll
            for (int i = 0; i < 4; ++i)
#pragma unroll
                for (int j = 0; j < 4; ++j)
                    acc[i][j] = fmaf(a[i], b[j], acc[i][j]);
        }
        __syncthreads();
    }

#pragma unroll
    for (int i = 0; i < 4; ++i) {
        const int r = row0 + ty * 4 + i;
        const float dscale = 1.0f / (rs[r] + 1.0f) + 1.0f;
        float4 o;
        o.x = fmaxf(acc[i][0] * dscale, 0.f);
        o.y = fmaxf(acc[i][1] * dscale, 0.f);
        o.z = fmaxf(acc[i][2] * dscale, 0.f);
        o.w = fmaxf(acc[i][3] * dscale, 0.f);
        *(float4*)(out + (size_t)r * EDIM + col0 + tx * 4) = o;
    }
}

extern "C" void kernel_launch(void* const* d_in, const int* in_sizes, int n_in,
                              void* d_out, int out_size, void* d_ws, size_t ws_size,
                              hipStream_t stream) {
    const float* adj = (const float*)d_in[0];   // [16384, 16384] fp32
    const float* x   = (const float*)d_in[1];   // [16384, 512]   fp32
    const float* W   = (const float*)d_in[2];   // [256, 512]     fp32
    float* out = (float*)d_out;                 // [16384, 256]   fp32
    float* rs  = (float*)d_ws;                  // [16384] rowsums

    rowsum_kernel<<<NROWS, 256, 0, stream>>>(adj, rs);

    dim3 grid(NROWS / GM, EDIM / GN);
    gemm_relu_kernel<<<grid, 256, 0, stream>>>(x, W, rs, out);
}

// Round 3
// 178.171 us; speedup vs baseline: 1.4412x; 1.4412x over previous
//
#include <hip/hip_runtime.h>
#include <hip/hip_bf16.h>

#define NROWS 16384
#define KDIM  512
#define EDIM  256
#define BM    64
#define BK    64

typedef __attribute__((ext_vector_type(8))) short  short8;
typedef __attribute__((ext_vector_type(4))) float  floatx4;
typedef __attribute__((ext_vector_type(4))) unsigned short ushort4_t;

// fp32 -> bf16 round-to-nearest-even (bit trick; data has no NaN/Inf)
static __device__ __forceinline__ unsigned short f2bf(float f) {
    union { float f; unsigned int u; } v; v.f = f;
    return (unsigned short)((v.u + 0x7FFFu + ((v.u >> 16) & 1u)) >> 16);
}

// ---------------------------------------------------------------------------
// Fused kernel: one block per 64 output rows (grid=256 = 1 block/CU).
// Phase 1: wave w (of 8) streams adj rows [m0+8w, m0+8w+8) (64 KB each,
//          nontemporal), wave-shuffle reduce -> dsc[] in LDS.
// Phase 2: bf16 MFMA GEMM, block tile 64(M) x 256(N=full), BK=64,
//          8 waves in 2(M) x 4(N) grid, wave = 32x64 = 2x4 fragments of
//          16x16x32. A (x) and B (W) converted fp32->bf16 during staging.
//          LDS tiles XOR-swizzled so stride-128B ds_read_b128 is conflict-free.
// Epilogue: d-scale + relu.
// ---------------------------------------------------------------------------
__global__ __launch_bounds__(512) void fused_kernel(const float* __restrict__ adj,
                                                    const float* __restrict__ x,
                                                    const float* __restrict__ W,
                                                    float* __restrict__ out) {
    __shared__ unsigned short As[BM * BK];     // x tile, bf16, swizzled (8 KB)
    __shared__ unsigned short Bs[EDIM * BK];   // W tile, bf16, swizzled (32 KB)
    __shared__ float dsc[BM];

    const int m0 = blockIdx.x * BM;
    const int t  = threadIdx.x;
    const int l  = t & 63;
    const int w  = t >> 6;       // wave 0..7

    // ---------------- phase 1: rowsums -> dsc ----------------
    {
        const floatx4* p = (const floatx4*)(adj + (size_t)(m0 + w * 8) * NROWS);
#pragma unroll
        for (int rr = 0; rr < 8; ++rr) {
            const floatx4* q = p + (size_t)rr * (NROWS / 4);
            float s0 = 0.f, s1 = 0.f, s2 = 0.f, s3 = 0.f;
#pragma unroll 4
            for (int i = 0; i < 64; i += 4) {
                floatx4 v0 = __builtin_nontemporal_load(&q[l + (i + 0) * 64]);
                floatx4 v1 = __builtin_nontemporal_load(&q[l + (i + 1) * 64]);
                floatx4 v2 = __builtin_nontemporal_load(&q[l + (i + 2) * 64]);
                floatx4 v3 = __builtin_nontemporal_load(&q[l + (i + 3) * 64]);
                s0 += (v0.x + v0.y) + (v0.z + v0.w);
                s1 += (v1.x + v1.y) + (v1.z + v1.w);
                s2 += (v2.x + v2.y) + (v2.z + v2.w);
                s3 += (v3.x + v3.y) + (v3.z + v3.w);
            }
            float s = (s0 + s1) + (s2 + s3);
#pragma unroll
            for (int off = 32; off > 0; off >>= 1)
                s += __shfl_down(s, off, 64);
            if (l == 0) dsc[w * 8 + rr] = 1.0f / (s + 1.0f) + 1.0f;
        }
    }

    // ---------------- phase 2: GEMM ----------------
    const int lr = l & 15;       // fragment row/col index
    const int lh = l >> 4;       // k-group
    const int wm = w >> 2;       // 0..1  (M half)
    const int wn = w & 3;        // 0..3  (N quarter)

    floatx4 acc[2][4] = {};

    for (int k0 = 0; k0 < KDIM; k0 += BK) {
        if (k0) __syncthreads();

        // --- stage A: 64 rows x 64 k, fp32 -> bf16 (2 passes) ---
        {
            const int kq = (t & 15) * 4;   // k offset (floats), multiple of 4
            int r = t >> 4;                // 0..31
#pragma unroll
            for (int p = 0; p < 2; ++p, r += 32) {
                float4 v = *(const float4*)(x + (size_t)(m0 + r) * KDIM + k0 + kq);
                ushort4_t o = { f2bf(v.x), f2bf(v.y), f2bf(v.z), f2bf(v.w) };
                const int idx = (r * BK + kq) ^ ((r & 7) << 3);
                *(ushort4_t*)&As[idx] = o;
            }
        }
        // --- stage B: 256 rows x 64 k, fp32 -> bf16 (8 passes, full tile) ---
        {
            const int kq = (t & 15) * 4;
            int n = t >> 4;                // 0..31
#pragma unroll
            for (int p = 0; p < 8; ++p, n += 32) {
                float4 v = *(const float4*)(W + (size_t)n * KDIM + k0 + kq);
                ushort4_t o = { f2bf(v.x), f2bf(v.y), f2bf(v.z), f2bf(v.w) };
                const int idx = (n * BK + kq) ^ ((n & 7) << 3);
                *(ushort4_t*)&Bs[idx] = o;
            }
        }
        __syncthreads();

        // --- compute: 2 k-chunks of 32, 8 MFMA each ---
#pragma unroll
        for (int kc = 0; kc < 2; ++kc) {
            const int kk = kc * 32 + lh * 8;
            short8 a[2], b[4];
#pragma unroll
            for (int mf = 0; mf < 2; ++mf) {
                const int r = wm * 32 + mf * 16 + lr;
                a[mf] = *(const short8*)&As[(r * BK + kk) ^ ((r & 7) << 3)];
            }
#pragma unroll
            for (int nf = 0; nf < 4; ++nf) {
                const int n = wn * 64 + nf * 16 + lr;
                b[nf] = *(const short8*)&Bs[(n * BK + kk) ^ ((n & 7) << 3)];
            }
#pragma unroll
            for (int mf = 0; mf < 2; ++mf)
#pragma unroll
                for (int nf = 0; nf < 4; ++nf)
                    acc[mf][nf] = __builtin_amdgcn_mfma_f32_16x16x32_bf16(
                        a[mf], b[nf], acc[mf][nf], 0, 0, 0);
        }
    }

    // ---------------- epilogue: d-scale + relu ----------------
    // C/D layout (m89-verified): col = lane&15, row = (lane>>4)*4 + reg
#pragma unroll
    for (int mf = 0; mf < 2; ++mf) {
#pragma unroll
        for (int j = 0; j < 4; ++j) {
            const int rloc = wm * 32 + mf * 16 + lh * 4 + j;
            const float dscale = dsc[rloc];
            const size_t row = m0 + rloc;
#pragma unroll
            for (int nf = 0; nf < 4; ++nf) {
                const int col = wn * 64 + nf * 16 + lr;
                out[row * EDIM + col] = fmaxf(acc[mf][nf][j] * dscale, 0.f);
            }
        }
    }
}

extern "C" void kernel_launch(void* const* d_in, const int* in_sizes, int n_in,
                              void* d_out, int out_size, void* d_ws, size_t ws_size,
                              hipStream_t stream) {
    const float* adj = (const float*)d_in[0];   // [16384, 16384] fp32
    const float* x   = (const float*)d_in[1];   // [16384, 512]   fp32
    const float* W   = (const float*)d_in[2];   // [256, 512]     fp32
    float* out = (float*)d_out;                 // [16384, 256]   fp32

    fused_kernel<<<NROWS / BM, 512, 0, stream>>>(adj, x, W, out);
}